// Round 7
// baseline (886.450 us; speedup 1.0000x reference)
//
#include <hip/hip_runtime.h>

#define IMG   512
#define WIN   11
#define TW    64              // tile width  (output cols)
#define TH    16              // tile height (output rows)
#define HR    (TH + WIN - 1)  // 26 h-filtered rows
#define HP    68              // hbuf row pitch (dwords), 16B-aligned rows
#define FPL   (HR * HP)       // 1768 dwords per field
#define NT    256

// guarded float4 load of cols c..c+3 from one image row (zero outside)
__device__ __forceinline__ float4 loadg4(const float* __restrict__ rowp,
                                         int c, bool rowok) {
    float4 v = make_float4(0.f, 0.f, 0.f, 0.f);
    if (rowok) {
        if ((unsigned)c <= (unsigned)(IMG - 4)) {
            v = *reinterpret_cast<const float4*>(rowp + c);
        } else {
            if ((unsigned)(c + 0) < IMG) v.x = rowp[c + 0];
            if ((unsigned)(c + 1) < IMG) v.y = rowp[c + 1];
            if ((unsigned)(c + 2) < IMG) v.z = rowp[c + 2];
            if ((unsigned)(c + 3) < IMG) v.w = rowp[c + 3];
        }
    }
    return v;
}

__device__ __forceinline__ float ssim_pt(float mx, float my, float fss, float fxy) {
    const float t   = fmaf(my, my, mx * mx);    // mx^2 + my^2
    const float mxy = mx * my;
    const float sig = fss - t;                  // sxx + syy
    const float sxy = fxy - mxy;
    const float num = fmaf(2.f, mxy, 1e-4f) * fmaf(2.f, sxy, 9e-4f);
    const float den = (t + 1e-4f) * (sig + 9e-4f);
    return num * __builtin_amdgcn_rcpf(den);
}

// h-phase: 11-tap horizontal conv of 4 fields (x, y, x^2+y^2, x*y) straight
// from global via float4 register windows. EDGE=false -> no guards at all.
template<bool EDGE>
__device__ __forceinline__ void hphase(const float* __restrict__ xp,
                                       const float* __restrict__ yp,
                                       int row0, int col0, int tid,
                                       const float* __restrict__ w,
                                       float* __restrict__ hbuf)
{
    for (int task = tid; task < HR * 16; task += NT) {
        const int r  = task >> 4;              // 0..25
        const int q  = task & 15;
        const int gr = row0 - 5 + r;
        const float* xr = xp + (size_t)gr * IMG;
        const float* yr = yp + (size_t)gr * IMG;

        float sx[20], sy[20], sw[20];
        #pragma unroll
        for (int jj = 0; jj < 5; ++jj) {
            const int c = col0 + 4 * q - 8 + 4 * jj;
            float4 vx, vy;
            if (EDGE) {
                const bool rok = (unsigned)gr < IMG;
                vx = loadg4(xr, c, rok);
                vy = loadg4(yr, c, rok);
            } else {
                vx = *reinterpret_cast<const float4*>(xr + c);
                vy = *reinterpret_cast<const float4*>(yr + c);
            }
            sx[4*jj+0] = vx.x; sx[4*jj+1] = vx.y; sx[4*jj+2] = vx.z; sx[4*jj+3] = vx.w;
            sy[4*jj+0] = vy.x; sy[4*jj+1] = vy.y; sy[4*jj+2] = vy.z; sy[4*jj+3] = vy.w;
        }

        float h0[4] = {0.f, 0.f, 0.f, 0.f};
        float h1[4] = {0.f, 0.f, 0.f, 0.f};

        // fields x and y
        #pragma unroll
        for (int k = 0; k < WIN; ++k) {
            const float wk = w[k];
            #pragma unroll
            for (int j = 0; j < 4; ++j) {
                const int idx = j + k + 3;
                h0[j] = fmaf(wk, sx[idx], h0[j]);
                h1[j] = fmaf(wk, sy[idx], h1[j]);
            }
        }
        const int b = r * HP + 4 * q;
        *reinterpret_cast<float4*>(&hbuf[0*FPL + b]) = make_float4(h0[0], h0[1], h0[2], h0[3]);
        *reinterpret_cast<float4*>(&hbuf[1*FPL + b]) = make_float4(h1[0], h1[1], h1[2], h1[3]);

        // field x^2 + y^2
        #pragma unroll
        for (int e = 0; e < 20; ++e) sw[e] = fmaf(sy[e], sy[e], sx[e] * sx[e]);
        #pragma unroll
        for (int j = 0; j < 4; ++j) h0[j] = 0.f;
        #pragma unroll
        for (int k = 0; k < WIN; ++k) {
            const float wk = w[k];
            #pragma unroll
            for (int j = 0; j < 4; ++j)
                h0[j] = fmaf(wk, sw[j + k + 3], h0[j]);
        }
        *reinterpret_cast<float4*>(&hbuf[2*FPL + b]) = make_float4(h0[0], h0[1], h0[2], h0[3]);

        // field x*y
        #pragma unroll
        for (int e = 0; e < 20; ++e) sw[e] = sx[e] * sy[e];
        #pragma unroll
        for (int j = 0; j < 4; ++j) h0[j] = 0.f;
        #pragma unroll
        for (int k = 0; k < WIN; ++k) {
            const float wk = w[k];
            #pragma unroll
            for (int j = 0; j < 4; ++j)
                h0[j] = fmaf(wk, sw[j + k + 3], h0[j]);
        }
        *reinterpret_cast<float4*>(&hbuf[3*FPL + b]) = make_float4(h0[0], h0[1], h0[2], h0[3]);
    }
}

// ---------------------------------------------------------------------------
// One block = 64x16 output tile. hbuf 28.3 KB f32 -> 5 blocks/CU (20 waves).
// v-phase: 11-tap vertical conv via ds_read_b128, SSIM map, block sum,
// global atomic + counter-based single-kernel finalize.
// ---------------------------------------------------------------------------
__global__ __launch_bounds__(NT, 5)
void ssim_fused(const float* __restrict__ x,
                const float* __restrict__ y,
                const float* __restrict__ kern,
                float* __restrict__ accum,
                int*   __restrict__ counter,
                float* __restrict__ out,
                float invN, int nBlocks)
{
    __shared__ __align__(16) float hbuf[4 * FPL];   // 28,288 B
    __shared__ float wsum[NT / 64];

    const int tid   = threadIdx.x;
    const int bid   = blockIdx.x;
    const int plane = bid >> 8;                 // 256 tiles per plane
    const int rem   = bid & 255;
    const int row0  = (rem >> 3) * TH;          // 32 tile-rows
    const int col0  = (rem & 7)  * TW;          // 8 tile-cols

    const float* __restrict__ xp = x + (size_t)plane * (IMG * IMG);
    const float* __restrict__ yp = y + (size_t)plane * (IMG * IMG);

    // 1D separable weights: w[i] = k2[i][5] / sqrt(k2[5][5])
    float w[WIN];
    {
        const float cinv = rsqrtf(kern[5 * WIN + 5]);
        #pragma unroll
        for (int i = 0; i < WIN; ++i) w[i] = kern[i * WIN + 5] * cinv;
    }

    const bool edge = (row0 == 0) | (row0 == IMG - TH) |
                      (col0 == 0) | (col0 == IMG - TW);
    if (edge) hphase<true >(xp, yp, row0, col0, tid, w, hbuf);
    else      hphase<false>(xp, yp, row0, col0, tid, w, hbuf);

    __syncthreads();

    // ---- v-phase: thread -> (quad q, output row rr), 4 outputs ----
    float lsum = 0.f;
    {
        const int q  = tid & 15;
        const int rr = tid >> 4;                // 0..15
        float aX[4] = {0.f, 0.f, 0.f, 0.f};
        float aY[4] = {0.f, 0.f, 0.f, 0.f};
        float aS[4] = {0.f, 0.f, 0.f, 0.f};
        float aP[4] = {0.f, 0.f, 0.f, 0.f};

        #pragma unroll
        for (int t = 0; t < WIN; ++t) {
            const int b = (rr + t) * HP + 4 * q;
            const float wk = w[t];
            const float4 vX = *reinterpret_cast<const float4*>(&hbuf[0*FPL + b]);
            const float4 vY = *reinterpret_cast<const float4*>(&hbuf[1*FPL + b]);
            const float4 vS = *reinterpret_cast<const float4*>(&hbuf[2*FPL + b]);
            const float4 vP = *reinterpret_cast<const float4*>(&hbuf[3*FPL + b]);
            aX[0] = fmaf(wk, vX.x, aX[0]); aX[1] = fmaf(wk, vX.y, aX[1]);
            aX[2] = fmaf(wk, vX.z, aX[2]); aX[3] = fmaf(wk, vX.w, aX[3]);
            aY[0] = fmaf(wk, vY.x, aY[0]); aY[1] = fmaf(wk, vY.y, aY[1]);
            aY[2] = fmaf(wk, vY.z, aY[2]); aY[3] = fmaf(wk, vY.w, aY[3]);
            aS[0] = fmaf(wk, vS.x, aS[0]); aS[1] = fmaf(wk, vS.y, aS[1]);
            aS[2] = fmaf(wk, vS.z, aS[2]); aS[3] = fmaf(wk, vS.w, aS[3]);
            aP[0] = fmaf(wk, vP.x, aP[0]); aP[1] = fmaf(wk, vP.y, aP[1]);
            aP[2] = fmaf(wk, vP.z, aP[2]); aP[3] = fmaf(wk, vP.w, aP[3]);
        }

        #pragma unroll
        for (int e = 0; e < 4; ++e)
            lsum += ssim_pt(aX[e], aY[e], aS[e], aP[e]);
    }

    // ---- block reduction -> one atomic, counter-based finalize ----
    #pragma unroll
    for (int off = 32; off > 0; off >>= 1)
        lsum += __shfl_down(lsum, off, 64);
    if ((tid & 63) == 0) wsum[tid >> 6] = lsum;
    __syncthreads();
    if (tid == 0) {
        const float s = wsum[0] + wsum[1] + wsum[2] + wsum[3];
        atomicAdd(accum, s);
        __threadfence();
        const int old = atomicAdd(counter, 1);
        if (old == nBlocks - 1) {
            const float tot = atomicAdd(accum, 0.0f);   // coherent read
            out[0] = 1.0f - tot * invN;
        }
    }
}

extern "C" void kernel_launch(void* const* d_in, const int* in_sizes, int n_in,
                              void* d_out, int out_size, void* d_ws, size_t ws_size,
                              hipStream_t stream)
{
    const float* x    = (const float*)d_in[0];
    const float* y    = (const float*)d_in[1];
    const float* kern = (const float*)d_in[2];
    float* out     = (float*)d_out;
    float* accum   = (float*)d_ws;
    int*   counter = (int*)d_ws + 1;

    const int planes  = in_sizes[0] / (IMG * IMG);   // B*C = 64
    const int nBlocks = planes * 256;                // 16384

    hipMemsetAsync(d_ws, 0, 2 * sizeof(float), stream);
    ssim_fused<<<nBlocks, NT, 0, stream>>>(
        x, y, kern, accum, counter, out,
        1.0f / ((float)planes * IMG * IMG), nBlocks);
}